// Round 4
// baseline (138.965 us; speedup 1.0000x reference)
//
#include <hip/hip_runtime.h>
#include <hip/hip_bf16.h>
#include <stdint.h>

// ---------------------------------------------------------------------------
// MultiModalInputEmbeddings. R4: counted-vmcnt raw-barrier K-loop (T4) in both
// GEMMs; gather fused into GEMM1 via fp32 reg-staging (T14 issue-early /
// write-late). 5 kernels: prep, compact, gemm1, gemm2(splitK), assemble.
// ---------------------------------------------------------------------------

typedef __bf16 bf16x8 __attribute__((ext_vector_type(8)));
typedef float f32x4 __attribute__((ext_vector_type(4)));

__device__ __forceinline__ unsigned short f2bf(float f) {
  union { float f; unsigned int u; } c; c.f = f;
  unsigned int u = c.u;
  return (unsigned short)((u + 0x7FFFu + ((u >> 16) & 1u)) >> 16);  // RNE
}
__device__ __forceinline__ float bf2f(unsigned short b) {
  union { unsigned int u; float f; } c; c.u = ((unsigned int)b) << 16;
  return c.f;
}
__device__ __forceinline__ unsigned pk2(float a, float b) {
  return (unsigned)f2bf(a) | ((unsigned)f2bf(b) << 16);
}
__device__ __forceinline__ void barrier_sync() {
  asm volatile("" ::: "memory");
  __builtin_amdgcn_sched_barrier(0);
  __builtin_amdgcn_s_barrier();
  __builtin_amdgcn_sched_barrier(0);
  asm volatile("" ::: "memory");
}

// ---- prep: both weight transposes (fp32 [R][C] -> bf16 [C][R]) + zero ctr --
__global__ __launch_bounds__(256) void k_prep(
    const float* __restrict__ fc1_w, const float* __restrict__ fc2_w,
    unsigned short* __restrict__ w1t, unsigned short* __restrict__ w2t,
    int* __restrict__ counter) {
  if (blockIdx.x == 0 && threadIdx.x == 0) *counter = 0;
  __shared__ float tile[32][33];
  int b = blockIdx.x;
  const float* src;
  unsigned short* dst;
  int R, C, bx, by;
  if (b < 2304) {  // fc1_w: 768 x 3072
    src = fc1_w; dst = w1t; R = 768; C = 3072;
    bx = (b % 96) * 32; by = (b / 96) * 32;
  } else {         // fc2_w: 3072 x 768
    b -= 2304;
    src = fc2_w; dst = w2t; R = 3072; C = 768;
    bx = (b % 24) * 32; by = (b / 24) * 32;
  }
  int tx = threadIdx.x & 31;
  int ty = threadIdx.x >> 5;
#pragma unroll
  for (int i = 0; i < 4; i++) {
    int r = by + ty + i * 8;
    tile[ty + i * 8][tx] = src[(size_t)r * C + bx + tx];
  }
  __syncthreads();
#pragma unroll
  for (int i = 0; i < 4; i++) {
    int c = bx + ty + i * 8;
    dst[(size_t)c * R + by + tx] = f2bf(tile[tx][ty + i * 8]);
  }
}

// ---- compact: build list of smiles-token indices -------------------------
__global__ void k_compact(const int* __restrict__ tt, int* __restrict__ counter,
                          int* __restrict__ idx, int* __restrict__ slot, int BS) {
  int t = blockIdx.x * 256 + threadIdx.x;
  if (t >= BS) return;
  if (tt[t] == 1) {
    int s = atomicAdd(counter, 1);
    idx[s] = t;
    slot[t] = s;
  }
}

// ---- GEMM1: A = fps rows via idx (fp32 -> bf16 reg-staged), B = w1t --------
// [n_pad,768] x [768,3072] -> h1 bf16 (+bias,+relu). 128x128 tile, BK=64.
__global__ __launch_bounds__(256) void k_gemm1(
    const float* __restrict__ fps, const int* __restrict__ idx,
    const unsigned short* __restrict__ BT,  // w1t [3072][768]
    const float* __restrict__ bias,
    unsigned short* __restrict__ C,         // h1 [cap][3072]
    const int* __restrict__ counter, int cap) {
  int n = *counter;
  int n_pad = (n + 127) & ~127;
  if (n_pad > cap) n_pad = cap;
  const int mb = n_pad >> 7;

  // XCD rect: 24 n-cols, C_CH=2, A_CH=4, CLEN=12
  const int bid = blockIdx.x;
  const int xcd = bid & 7;
  const int j = bid >> 3;
  const int mc = xcd >> 1, cc = xcd & 1;
  const int q = mb >> 2, r = mb & 3;
  const int mlen = q + (mc < r ? 1 : 0);
  const int mbase = mc * q + (mc < r ? mc : r);
  if (j >= mlen * 12) return;
  const int m_blk = mbase + j / 12;
  const int nb = cc * 12 + j % 12;
  const int m0 = m_blk * 128, n0 = nb * 128;

  __shared__ __attribute__((aligned(128))) char smem[65536];
  auto lds = (__attribute__((address_space(3))) char*)smem;
  const int t = threadIdx.x;
  const int wave = t >> 6, lane = t & 63;
  const int wm = (wave >> 1) * 64, wn = (wave & 1) * 64;

  // per-thread A source rows (fixed across K): chunks c = i*256+t, r = c>>3
  const float* arow[4];
  bool avalid[4];
#pragma unroll
  for (int i = 0; i < 4; i++) {
    int c = i * 256 + t;
    int rr = c >> 3;
    int koff = ((c & 7) ^ (rr & 7)) << 3;   // pre-swizzled k-chunk
    int grow = m0 + rr;
    avalid[i] = grow < n;
    arow[i] = fps + (size_t)(avalid[i] ? idx[grow] : 0) * 768 + koff;
  }

  f32x4 acc[4][4] = {};
  float4 av[4][2];

  auto loadA = [&](int kt) {
#pragma unroll
    for (int i = 0; i < 4; i++) {
      if (avalid[i]) {
        const float4* p = (const float4*)(arow[i] + kt * 64);
        av[i][0] = p[0];
        av[i][1] = p[1];
      } else {
        av[i][0] = make_float4(0.f, 0.f, 0.f, 0.f);
        av[i][1] = make_float4(0.f, 0.f, 0.f, 0.f);
      }
    }
  };
  auto stageB = [&](int kt, int bufbase) {
#pragma unroll
    for (int i = 0; i < 4; i++) {
      int c = i * 256 + t;
      int rr = c >> 3;
      const unsigned short* gb =
          BT + (size_t)(n0 + rr) * 768 + kt * 64 + (((c & 7) ^ (rr & 7)) << 3);
      __builtin_amdgcn_global_load_lds(
          (const __attribute__((address_space(1))) void*)gb,
          (__attribute__((address_space(3))) void*)(lds + bufbase + 16384 +
                                                    i * 4096 + wave * 1024),
          16, 0, 0);
    }
  };
  auto writeA = [&](int bufbase) {
#pragma unroll
    for (int i = 0; i < 4; i++) {
      int c = i * 256 + t;
      uint4 w;
      w.x = pk2(av[i][0].x, av[i][0].y);
      w.y = pk2(av[i][0].z, av[i][0].w);
      w.z = pk2(av[i][1].x, av[i][1].y);
      w.w = pk2(av[i][1].z, av[i][1].w);
      *(uint4*)(smem + bufbase + c * 16) = w;
    }
  };
  auto compute = [&](int bufbase) {
#pragma unroll
    for (int kk = 0; kk < 2; kk++) {
      bf16x8 af[4], bfr[4];
      int kbyte = (kk * 32 + ((lane >> 4) * 8)) * 2;
#pragma unroll
      for (int mi = 0; mi < 4; mi++) {
        int rr = wm + mi * 16 + (lane & 15);
        af[mi] = *(const bf16x8*)(smem + bufbase + rr * 128 + (kbyte ^ ((rr & 7) << 4)));
      }
#pragma unroll
      for (int ni = 0; ni < 4; ni++) {
        int rr = wn + ni * 16 + (lane & 15);
        bfr[ni] = *(const bf16x8*)(smem + bufbase + 16384 + rr * 128 + (kbyte ^ ((rr & 7) << 4)));
      }
#pragma unroll
      for (int mi = 0; mi < 4; mi++)
#pragma unroll
        for (int ni = 0; ni < 4; ni++)
          acc[mi][ni] = __builtin_amdgcn_mfma_f32_16x16x32_bf16(
              af[mi], bfr[ni], acc[mi][ni], 0, 0, 0);
    }
  };

  // prologue: A(0)->regs, B(0)->LDS, A(0)->LDS
  loadA(0);
  stageB(0, 0);
  writeA(0);
  asm volatile("s_waitcnt lgkmcnt(0)" ::: "memory");

  for (int it = 0; it < 12; ++it) {
    const int cur = it & 1, nxt = cur ^ 1;
    if (it + 1 < 12) {
      loadA(it + 1);               // issue-early (T14)
      stageB(it + 1, nxt * 32768);
      __builtin_amdgcn_sched_barrier(0);
      asm volatile("s_waitcnt vmcnt(12)" ::: "memory");  // cur's B landed
    } else {
      asm volatile("s_waitcnt vmcnt(0)" ::: "memory");   // tail drain
    }
    barrier_sync();
    compute(cur * 32768);
    if (it + 1 < 12) writeA(nxt * 32768);  // write-late (T14)
    asm volatile("s_waitcnt lgkmcnt(0)" ::: "memory");
    barrier_sync();
  }

  // epilogue: bias + relu, bf16 store
#pragma unroll
  for (int ni = 0; ni < 4; ni++) {
    int col = n0 + wn + ni * 16 + (lane & 15);
    float bv = bias[col];
#pragma unroll
    for (int mi = 0; mi < 4; mi++) {
#pragma unroll
      for (int j2 = 0; j2 < 4; j2++) {
        int row = m0 + wm + mi * 16 + ((lane >> 4) * 4) + j2;
        float v = acc[mi][ni][j2] + bv;
        v = v > 0.f ? v : 0.f;
        C[(size_t)row * 3072 + col] = f2bf(v);
      }
    }
  }
}

// ---- GEMM2: [cap,3072] x [3072,768], split-K KS slices -> bf16 partials ----
template <int NB, int KS>
__global__ __launch_bounds__(256) void k_gemm2(
    const unsigned short* __restrict__ A,   // h1 [cap][3072]
    const unsigned short* __restrict__ BT,  // w2t [768][3072]
    unsigned short* __restrict__ C,         // partials [KS][cap][768]
    const int* __restrict__ counter, int cap) {
  int n = *counter;
  int n_pad = (n + 127) & ~127;
  if (n_pad > cap) n_pad = cap;
  const int mb = n_pad >> 7;

  constexpr int NCOL = NB * KS;
  constexpr int C_CH = (KS == 4) ? 4 : 2;
  constexpr int A_CH = 8 / C_CH;
  constexpr int CLEN = NCOL / C_CH;

  const int bid = blockIdx.x;
  const int xcd = bid & 7;
  const int j = bid >> 3;
  const int mc = xcd / C_CH, cc = xcd % C_CH;
  const int q = mb / A_CH, r = mb % A_CH;
  const int mlen = q + (mc < r ? 1 : 0);
  const int mbase = mc * q + (mc < r ? mc : r);
  if (j >= mlen * CLEN) return;
  const int m_blk = mbase + j / CLEN;
  const int c_blk = cc * CLEN + j % CLEN;
  const int ks = c_blk / NB;
  const int nb = c_blk % NB;
  const int m0 = m_blk * 128, n0 = nb * 128;
  const int k0g = ks * 768;

  __shared__ __attribute__((aligned(128))) char smem[65536];
  auto lds = (__attribute__((address_space(3))) char*)smem;
  const int t = threadIdx.x;
  const int wave = t >> 6, lane = t & 63;
  const int wm = (wave >> 1) * 64, wn = (wave & 1) * 64;

  f32x4 acc[4][4] = {};

  auto stage = [&](int kt, int bufbase) {
#pragma unroll
    for (int i = 0; i < 4; i++) {
      int c = i * 256 + t;
      int rr = c >> 3;
      int k8 = ((c & 7) ^ (rr & 7)) << 3;
      const unsigned short* ga = A + (size_t)(m0 + rr) * 3072 + k0g + kt * 64 + k8;
      __builtin_amdgcn_global_load_lds(
          (const __attribute__((address_space(1))) void*)ga,
          (__attribute__((address_space(3))) void*)(lds + bufbase + i * 4096 + wave * 1024),
          16, 0, 0);
    }
#pragma unroll
    for (int i = 0; i < 4; i++) {
      int c = i * 256 + t;
      int rr = c >> 3;
      int k8 = ((c & 7) ^ (rr & 7)) << 3;
      const unsigned short* gb = BT + (size_t)(n0 + rr) * 3072 + k0g + kt * 64 + k8;
      __builtin_amdgcn_global_load_lds(
          (const __attribute__((address_space(1))) void*)gb,
          (__attribute__((address_space(3))) void*)(lds + bufbase + 16384 + i * 4096 + wave * 1024),
          16, 0, 0);
    }
  };

  stage(0, 0);
  for (int it = 0; it < 12; ++it) {
    const int cur = it & 1, nxt = cur ^ 1;
    if (it + 1 < 12) {
      stage(it + 1, nxt * 32768);
      __builtin_amdgcn_sched_barrier(0);
      asm volatile("s_waitcnt vmcnt(8)" ::: "memory");  // cur's 8 landed
    } else {
      asm volatile("s_waitcnt vmcnt(0)" ::: "memory");
    }
    barrier_sync();
#pragma unroll
    for (int kk = 0; kk < 2; kk++) {
      bf16x8 af[4], bfr[4];
      int kbyte = (kk * 32 + ((lane >> 4) * 8)) * 2;
      const int bufbase = cur * 32768;
#pragma unroll
      for (int mi = 0; mi < 4; mi++) {
        int rr = wm + mi * 16 + (lane & 15);
        af[mi] = *(const bf16x8*)(smem + bufbase + rr * 128 + (kbyte ^ ((rr & 7) << 4)));
      }
#pragma unroll
      for (int ni = 0; ni < 4; ni++) {
        int rr = wn + ni * 16 + (lane & 15);
        bfr[ni] = *(const bf16x8*)(smem + bufbase + 16384 + rr * 128 + (kbyte ^ ((rr & 7) << 4)));
      }
#pragma unroll
      for (int mi = 0; mi < 4; mi++)
#pragma unroll
        for (int ni = 0; ni < 4; ni++)
          acc[mi][ni] = __builtin_amdgcn_mfma_f32_16x16x32_bf16(
              af[mi], bfr[ni], acc[mi][ni], 0, 0, 0);
    }
    asm volatile("s_waitcnt lgkmcnt(0)" ::: "memory");
    barrier_sync();
  }

#pragma unroll
  for (int ni = 0; ni < 4; ni++) {
    int col = n0 + wn + ni * 16 + (lane & 15);
#pragma unroll
    for (int mi = 0; mi < 4; mi++) {
#pragma unroll
      for (int j2 = 0; j2 < 4; j2++) {
        int row = m0 + wm + mi * 16 + ((lane >> 4) * 4) + j2;
        C[((size_t)ks * cap + row) * 768 + col] = f2bf(acc[mi][ni][j2]);
      }
    }
  }
}

// ---- assembly: branch select (+split-K reduce +fc2 bias) + emb + LN -------
template <int KS>
__global__ __launch_bounds__(256) void k_assemble(
    const unsigned short* __restrict__ sout, const float* __restrict__ fc2b,
    const int* __restrict__ slot,
    const int* __restrict__ ttid, const int* __restrict__ word,
    const float* __restrict__ values, const int* __restrict__ posid,
    const float* __restrict__ prop, const float* __restrict__ valw,
    const float* __restrict__ valb, const float* __restrict__ pose,
    const float* __restrict__ tye, const float* __restrict__ lng,
    const float* __restrict__ lnb, float* __restrict__ out, int BS, int cap) {
  int wave = threadIdx.x >> 6, lane = threadIdx.x & 63;
  int t = blockIdx.x * 4 + wave;
  if (t >= BS) return;
  int tt = ttid[t];

  float v[12];
  if (tt == 1) {
    int sl = slot[t];
    const ushort4* pr[KS];
#pragma unroll
    for (int p = 0; p < KS; p++)
      pr[p] = (const ushort4*)(sout + ((size_t)p * cap + sl) * 768);
    const float4* b4 = (const float4*)fc2b;
#pragma unroll
    for (int i = 0; i < 3; i++) {
      float4 b = b4[lane + (i << 6)];
      float a0 = b.x, a1 = b.y, a2 = b.z, a3 = b.w;
#pragma unroll
      for (int p = 0; p < KS; p++) {
        ushort4 u = pr[p][lane + (i << 6)];
        a0 += bf2f(u.x); a1 += bf2f(u.y); a2 += bf2f(u.z); a3 += bf2f(u.w);
      }
      v[4 * i] = a0; v[4 * i + 1] = a1; v[4 * i + 2] = a2; v[4 * i + 3] = a3;
    }
  } else if (tt == 0) {
    const float4* row = (const float4*)(prop + (size_t)word[t] * 768);
#pragma unroll
    for (int i = 0; i < 3; i++) {
      float4 x = row[lane + (i << 6)];
      v[4 * i] = x.x; v[4 * i + 1] = x.y; v[4 * i + 2] = x.z; v[4 * i + 3] = x.w;
    }
  } else if (tt == 2) {
    float val = values[t];
#pragma unroll
    for (int i = 0; i < 3; i++) {
      float4 w = ((const float4*)valw)[lane + (i << 6)];
      float4 b = ((const float4*)valb)[lane + (i << 6)];
      v[4 * i] = val * w.x + b.x; v[4 * i + 1] = val * w.y + b.y;
      v[4 * i + 2] = val * w.z + b.z; v[4 * i + 3] = val * w.w + b.w;
    }
  } else {
#pragma unroll
    for (int j = 0; j < 12; j++) v[j] = 0.f;
  }

  const float4* p4 = (const float4*)(pose + (size_t)posid[t] * 768);
  const float4* ty4 = (const float4*)(tye + (size_t)tt * 768);
#pragma unroll
  for (int i = 0; i < 3; i++) {
    float4 p = p4[lane + (i << 6)];
    float4 y = ty4[lane + (i << 6)];
    v[4 * i] += p.x + y.x; v[4 * i + 1] += p.y + y.y;
    v[4 * i + 2] += p.z + y.z; v[4 * i + 3] += p.w + y.w;
  }

  float s = 0.f;
#pragma unroll
  for (int j = 0; j < 12; j++) s += v[j];
#pragma unroll
  for (int o = 32; o >= 1; o >>= 1) s += __shfl_xor(s, o);
  float mu = s * (1.0f / 768.0f);

  float qv = 0.f;
#pragma unroll
  for (int j = 0; j < 12; j++) { float d = v[j] - mu; qv += d * d; }
#pragma unroll
  for (int o = 32; o >= 1; o >>= 1) qv += __shfl_xor(qv, o);
  float rs = 1.0f / sqrtf(qv * (1.0f / 768.0f) + 1e-12f);

  float4* o4 = (float4*)(out + (size_t)t * 768);
#pragma unroll
  for (int i = 0; i < 3; i++) {
    float4 g = ((const float4*)lng)[lane + (i << 6)];
    float4 b = ((const float4*)lnb)[lane + (i << 6)];
    float4 r;
    r.x = (v[4 * i] - mu) * rs * g.x + b.x;
    r.y = (v[4 * i + 1] - mu) * rs * g.y + b.y;
    r.z = (v[4 * i + 2] - mu) * rs * g.z + b.z;
    r.w = (v[4 * i + 3] - mu) * rs * g.w + b.w;
    o4[lane + (i << 6)] = r;
  }
}

// ---------------------------------------------------------------------------
extern "C" void kernel_launch(void* const* d_in, const int* in_sizes, int n_in,
                              void* d_out, int out_size, void* d_ws, size_t ws_size,
                              hipStream_t stream) {
  const int BS = in_sizes[3];  // 64*512 = 32768 tokens
  const float* fps    = (const float*)d_in[2];
  const int*   word   = (const int*)d_in[3];
  const float* values = (const float*)d_in[4];
  const int*   tt     = (const int*)d_in[5];
  const int*   pos    = (const int*)d_in[6];
  const float* fc1_w  = (const float*)d_in[7];
  const float* fc1_b  = (const float*)d_in[8];
  const float* fc2_w  = (const float*)d_in[9];
  const float* fc2_b  = (const float*)d_in[10];
  const float* prop   = (const float*)d_in[11];
  const float* valw   = (const float*)d_in[12];
  const float* valb   = (const float*)d_in[13];
  const float* pose   = (const float*)d_in[14];
  const float* tye    = (const float*)d_in[15];
  const float* lng    = (const float*)d_in[16];
  const float* lnb    = (const float*)d_in[17];
  float* out = (float*)d_out;

  char* ws = (char*)d_ws;
  const size_t off_idx  = 256;
  const size_t off_slot = off_idx + (size_t)BS * 4;
  const size_t off_w1t  = off_slot + (size_t)BS * 4;
  const size_t off_w2t  = off_w1t + (size_t)768 * 3072 * 2;
  const size_t off_h1   = off_w2t + (size_t)3072 * 768 * 2;
  const size_t fixed    = off_h1;
  size_t avail = ws_size > fixed ? ws_size - fixed : 0;

  // split-K(4): cap=8192 rows of h1(bf16) + 4x bf16 partials
  const size_t per_tok4 = 3072 * 2 + 4 * 768 * 2;  // 12288
  const bool splitk = avail >= (size_t)8192 * per_tok4;

  int cap;
  if (splitk) {
    cap = 8192;
  } else {
    const size_t per_tok1 = 3072 * 2 + 768 * 2;    // 7680
    long c = (long)(avail / per_tok1);
    c &= ~511L;
    if (c > BS) c = BS;
    if (c < 512) c = 512;
    cap = (int)c;
  }
  const int MBcap = cap / 128;

  const size_t off_sout = off_h1 + (size_t)cap * 3072 * 2;

  int* counter = (int*)(ws + 0);
  int* idx     = (int*)(ws + off_idx);
  int* slot    = (int*)(ws + off_slot);
  unsigned short* w1t = (unsigned short*)(ws + off_w1t);
  unsigned short* w2t = (unsigned short*)(ws + off_w2t);
  unsigned short* h1  = (unsigned short*)(ws + off_h1);
  unsigned short* sout = (unsigned short*)(ws + off_sout);

  k_prep<<<4608, 256, 0, stream>>>(fc1_w, fc2_w, w1t, w2t, counter);
  k_compact<<<(BS + 255) / 256, 256, 0, stream>>>(tt, counter, idx, slot, BS);

  // GEMM1 (gather fused): [n_pad,768] x [768,3072] -> h1 (+bias,+relu)
  k_gemm1<<<24 * MBcap, 256, 0, stream>>>(fps, idx, w1t, fc1_b, h1, counter, cap);

  if (splitk) {
    k_gemm2<6, 4><<<24 * MBcap, 256, 0, stream>>>(h1, w2t, sout, counter, cap);
    k_assemble<4><<<(BS + 3) / 4, 256, 0, stream>>>(
        sout, fc2_b, slot, tt, word, values, pos, prop, valw, valb, pose, tye,
        lng, lnb, out, BS, cap);
  } else {
    k_gemm2<6, 1><<<6 * MBcap, 256, 0, stream>>>(h1, w2t, sout, counter, cap);
    k_assemble<1><<<(BS + 3) / 4, 256, 0, stream>>>(
        sout, fc2_b, slot, tt, word, values, pos, prop, valw, valb, pose, tye,
        lng, lnb, out, BS, cap);
  }
}

// Round 5
// 121.183 us; speedup vs baseline: 1.1467x; 1.1467x over previous
//
#include <hip/hip_runtime.h>
#include <hip/hip_bf16.h>
#include <stdint.h>

// ---------------------------------------------------------------------------
// MultiModalInputEmbeddings. R5: revert R4's gather-fusion (fp32 A reg-staging
// caused 2x A bytes + L2 thrash + unhidden latency). Separate k_gather with
// bf16 A1 restored; both GEMMs use global_load_lds staging with the T4
// counted-vmcnt raw-barrier loop.
// ---------------------------------------------------------------------------

typedef __bf16 bf16x8 __attribute__((ext_vector_type(8)));
typedef float f32x4 __attribute__((ext_vector_type(4)));

__device__ __forceinline__ unsigned short f2bf(float f) {
  union { float f; unsigned int u; } c; c.f = f;
  unsigned int u = c.u;
  return (unsigned short)((u + 0x7FFFu + ((u >> 16) & 1u)) >> 16);  // RNE
}
__device__ __forceinline__ float bf2f(unsigned short b) {
  union { unsigned int u; float f; } c; c.u = ((unsigned int)b) << 16;
  return c.f;
}
__device__ __forceinline__ void barrier_sync() {
  asm volatile("" ::: "memory");
  __builtin_amdgcn_sched_barrier(0);
  __builtin_amdgcn_s_barrier();
  __builtin_amdgcn_sched_barrier(0);
  asm volatile("" ::: "memory");
}

// ---- prep: both weight transposes (fp32 [R][C] -> bf16 [C][R]) + zero ctr --
__global__ __launch_bounds__(256) void k_prep(
    const float* __restrict__ fc1_w, const float* __restrict__ fc2_w,
    unsigned short* __restrict__ w1t, unsigned short* __restrict__ w2t,
    int* __restrict__ counter) {
  if (blockIdx.x == 0 && threadIdx.x == 0) *counter = 0;
  __shared__ float tile[32][33];
  int b = blockIdx.x;
  const float* src;
  unsigned short* dst;
  int R, C, bx, by;
  if (b < 2304) {  // fc1_w: 768 x 3072
    src = fc1_w; dst = w1t; R = 768; C = 3072;
    bx = (b % 96) * 32; by = (b / 96) * 32;
  } else {         // fc2_w: 3072 x 768
    b -= 2304;
    src = fc2_w; dst = w2t; R = 3072; C = 768;
    bx = (b % 24) * 32; by = (b / 24) * 32;
  }
  int tx = threadIdx.x & 31;
  int ty = threadIdx.x >> 5;
#pragma unroll
  for (int i = 0; i < 4; i++) {
    int r = by + ty + i * 8;
    tile[ty + i * 8][tx] = src[(size_t)r * C + bx + tx];
  }
  __syncthreads();
#pragma unroll
  for (int i = 0; i < 4; i++) {
    int c = bx + ty + i * 8;
    dst[(size_t)c * R + by + tx] = f2bf(tile[tx][ty + i * 8]);
  }
}

// ---- compact: build list of smiles-token indices -------------------------
__global__ void k_compact(const int* __restrict__ tt, int* __restrict__ counter,
                          int* __restrict__ idx, int* __restrict__ slot, int BS) {
  int t = blockIdx.x * 256 + threadIdx.x;
  if (t >= BS) return;
  if (tt[t] == 1) {
    int s = atomicAdd(counter, 1);
    idx[s] = t;
    slot[t] = s;
  }
}

// ---- gather smiles fp rows -> compact bf16 A1 [cap][768] ------------------
__global__ __launch_bounds__(256) void k_gather(
    const float* __restrict__ fps, const int* __restrict__ idx,
    const int* __restrict__ counter, unsigned short* __restrict__ A1, int cap) {
  int wave = threadIdx.x >> 6, lane = threadIdx.x & 63;
  int s = blockIdx.x * 4 + wave;
  int n = *counter;
  int n_pad = (n + 127) & ~127;
  if (n_pad > cap) n_pad = cap;
  if (s >= n_pad) return;
  ushort4* dst = (ushort4*)(A1 + (size_t)s * 768);
  if (s < n) {
    const float4* srcr = (const float4*)(fps + (size_t)idx[s] * 768);
#pragma unroll
    for (int i = 0; i < 3; i++) {
      float4 v = srcr[lane + (i << 6)];
      ushort4 o;
      o.x = f2bf(v.x); o.y = f2bf(v.y); o.z = f2bf(v.z); o.w = f2bf(v.w);
      dst[lane + (i << 6)] = o;
    }
  } else {
    ushort4 z = {0, 0, 0, 0};
#pragma unroll
    for (int i = 0; i < 3; i++) dst[lane + (i << 6)] = z;
  }
}

// ---- bf16 MFMA GEMM, 128x128 tile, Kslice=768 (12 iters of BK=64) ---------
// T4 counted-vmcnt double-buffer loop. MODE 1: bf16 +bias+relu (GEMM1).
// MODE 0: bf16 partial, no bias (GEMM2 split-K slice ks).
template <int MODE, int NB, int KS, int AST, int BST>
__global__ __launch_bounds__(256) void k_gemm(
    const unsigned short* __restrict__ A,   // [cap][AST] bf16
    const unsigned short* __restrict__ BT,  // [N][BST]  bf16
    const float* __restrict__ bias,         // [N] (MODE1 only)
    unsigned short* __restrict__ C,
    const int* __restrict__ counter, int N, int cap) {
  int n = *counter;
  int n_pad = (n + 127) & ~127;
  if (n_pad > cap) n_pad = cap;
  const int mb = n_pad >> 7;  // active m-tiles

  constexpr int NCOL = NB * KS;
  constexpr int C_CH = (KS == 4) ? 4 : 2;  // col-chunks across XCDs
  constexpr int A_CH = 8 / C_CH;           // m-chunks across XCDs
  constexpr int CLEN = NCOL / C_CH;

  const int bid = blockIdx.x;
  const int xcd = bid & 7;
  const int j = bid >> 3;
  const int mc = xcd / C_CH, cc = xcd % C_CH;
  const int q = mb / A_CH, r = mb % A_CH;
  const int mlen = q + (mc < r ? 1 : 0);
  const int mbase = mc * q + (mc < r ? mc : r);
  if (j >= mlen * CLEN) return;
  const int m_blk = mbase + j / CLEN;
  const int c_blk = cc * CLEN + j % CLEN;
  const int ks = c_blk / NB;
  const int nb = c_blk % NB;
  const int m0 = m_blk * 128, n0 = nb * 128;
  const int k0g = ks * 768;

  __shared__ __attribute__((aligned(128))) char smem[65536];  // 2 x (A16K+B16K)
  auto lds = (__attribute__((address_space(3))) char*)smem;

  const int t = threadIdx.x;
  const int wave = t >> 6;
  const int lane = t & 63;
  const int wm = (wave >> 1) * 64;
  const int wn = (wave & 1) * 64;

  f32x4 acc[4][4] = {};

  auto stage = [&](int kt, int bufbase) {
#pragma unroll
    for (int i = 0; i < 4; i++) {
      int c = i * 256 + t;
      int rr = c >> 3;
      int k8 = ((c & 7) ^ (rr & 7)) << 3;  // inverse swizzle on global source
      const unsigned short* ga = A + (size_t)(m0 + rr) * AST + k0g + kt * 64 + k8;
      __builtin_amdgcn_global_load_lds(
          (const __attribute__((address_space(1))) void*)ga,
          (__attribute__((address_space(3))) void*)(lds + bufbase + i * 4096 + wave * 1024),
          16, 0, 0);
    }
#pragma unroll
    for (int i = 0; i < 4; i++) {
      int c = i * 256 + t;
      int rr = c >> 3;
      int k8 = ((c & 7) ^ (rr & 7)) << 3;
      const unsigned short* gb = BT + (size_t)(n0 + rr) * BST + k0g + kt * 64 + k8;
      __builtin_amdgcn_global_load_lds(
          (const __attribute__((address_space(1))) void*)gb,
          (__attribute__((address_space(3))) void*)(lds + bufbase + 16384 + i * 4096 + wave * 1024),
          16, 0, 0);
    }
  };

  stage(0, 0);
  for (int it = 0; it < 12; ++it) {
    const int cur = it & 1, nxt = cur ^ 1;
    if (it + 1 < 12) {
      stage(it + 1, nxt * 32768);
      __builtin_amdgcn_sched_barrier(0);
      asm volatile("s_waitcnt vmcnt(8)" ::: "memory");  // cur's 8 landed
    } else {
      asm volatile("s_waitcnt vmcnt(0)" ::: "memory");
    }
    barrier_sync();
    const int bufbase = cur * 32768;
#pragma unroll
    for (int kk = 0; kk < 2; kk++) {
      bf16x8 af[4], bfr[4];
      int kbyte = (kk * 32 + ((lane >> 4) * 8)) * 2;
#pragma unroll
      for (int mi = 0; mi < 4; mi++) {
        int rr = wm + mi * 16 + (lane & 15);
        af[mi] = *(const bf16x8*)(smem + bufbase + rr * 128 + (kbyte ^ ((rr & 7) << 4)));
      }
#pragma unroll
      for (int ni = 0; ni < 4; ni++) {
        int rr = wn + ni * 16 + (lane & 15);
        bfr[ni] = *(const bf16x8*)(smem + bufbase + 16384 + rr * 128 + (kbyte ^ ((rr & 7) << 4)));
      }
#pragma unroll
      for (int mi = 0; mi < 4; mi++)
#pragma unroll
        for (int ni = 0; ni < 4; ni++)
          acc[mi][ni] = __builtin_amdgcn_mfma_f32_16x16x32_bf16(
              af[mi], bfr[ni], acc[mi][ni], 0, 0, 0);
    }
    asm volatile("s_waitcnt lgkmcnt(0)" ::: "memory");
    barrier_sync();
  }

  // epilogue: bf16 store; MODE1 adds bias+relu, MODE0 is raw partial
#pragma unroll
  for (int ni = 0; ni < 4; ni++) {
    int col = n0 + wn + ni * 16 + (lane & 15);
    float bv = (MODE == 1) ? bias[col] : 0.f;
#pragma unroll
    for (int mi = 0; mi < 4; mi++) {
#pragma unroll
      for (int j2 = 0; j2 < 4; j2++) {
        int row = m0 + wm + mi * 16 + ((lane >> 4) * 4) + j2;
        float v = acc[mi][ni][j2] + bv;
        if constexpr (MODE == 1) {
          v = v > 0.f ? v : 0.f;
          C[(size_t)row * N + col] = f2bf(v);
        } else {
          C[((size_t)ks * cap + row) * N + col] = f2bf(v);
        }
      }
    }
  }
}

// ---- assembly: branch select (+split-K reduce +fc2 bias) + emb + LN -------
template <int KS>
__global__ __launch_bounds__(256) void k_assemble(
    const unsigned short* __restrict__ sout, const float* __restrict__ fc2b,
    const int* __restrict__ slot,
    const int* __restrict__ ttid, const int* __restrict__ word,
    const float* __restrict__ values, const int* __restrict__ posid,
    const float* __restrict__ prop, const float* __restrict__ valw,
    const float* __restrict__ valb, const float* __restrict__ pose,
    const float* __restrict__ tye, const float* __restrict__ lng,
    const float* __restrict__ lnb, float* __restrict__ out, int BS, int cap) {
  int wave = threadIdx.x >> 6, lane = threadIdx.x & 63;
  int t = blockIdx.x * 4 + wave;
  if (t >= BS) return;
  int tt = ttid[t];

  float v[12];
  if (tt == 1) {
    int sl = slot[t];
    const ushort4* pr[KS];
#pragma unroll
    for (int p = 0; p < KS; p++)
      pr[p] = (const ushort4*)(sout + ((size_t)p * cap + sl) * 768);
    const float4* b4 = (const float4*)fc2b;
#pragma unroll
    for (int i = 0; i < 3; i++) {
      float4 b = b4[lane + (i << 6)];
      float a0 = b.x, a1 = b.y, a2 = b.z, a3 = b.w;
#pragma unroll
      for (int p = 0; p < KS; p++) {
        ushort4 u = pr[p][lane + (i << 6)];
        a0 += bf2f(u.x); a1 += bf2f(u.y); a2 += bf2f(u.z); a3 += bf2f(u.w);
      }
      v[4 * i] = a0; v[4 * i + 1] = a1; v[4 * i + 2] = a2; v[4 * i + 3] = a3;
    }
  } else if (tt == 0) {
    const float4* row = (const float4*)(prop + (size_t)word[t] * 768);
#pragma unroll
    for (int i = 0; i < 3; i++) {
      float4 x = row[lane + (i << 6)];
      v[4 * i] = x.x; v[4 * i + 1] = x.y; v[4 * i + 2] = x.z; v[4 * i + 3] = x.w;
    }
  } else if (tt == 2) {
    float val = values[t];
#pragma unroll
    for (int i = 0; i < 3; i++) {
      float4 w = ((const float4*)valw)[lane + (i << 6)];
      float4 b = ((const float4*)valb)[lane + (i << 6)];
      v[4 * i] = val * w.x + b.x; v[4 * i + 1] = val * w.y + b.y;
      v[4 * i + 2] = val * w.z + b.z; v[4 * i + 3] = val * w.w + b.w;
    }
  } else {
#pragma unroll
    for (int j = 0; j < 12; j++) v[j] = 0.f;
  }

  const float4* p4 = (const float4*)(pose + (size_t)posid[t] * 768);
  const float4* ty4 = (const float4*)(tye + (size_t)tt * 768);
#pragma unroll
  for (int i = 0; i < 3; i++) {
    float4 p = p4[lane + (i << 6)];
    float4 y = ty4[lane + (i << 6)];
    v[4 * i] += p.x + y.x; v[4 * i + 1] += p.y + y.y;
    v[4 * i + 2] += p.z + y.z; v[4 * i + 3] += p.w + y.w;
  }

  float s = 0.f;
#pragma unroll
  for (int j = 0; j < 12; j++) s += v[j];
#pragma unroll
  for (int o = 32; o >= 1; o >>= 1) s += __shfl_xor(s, o);
  float mu = s * (1.0f / 768.0f);

  float qv = 0.f;
#pragma unroll
  for (int j = 0; j < 12; j++) { float d = v[j] - mu; qv += d * d; }
#pragma unroll
  for (int o = 32; o >= 1; o >>= 1) qv += __shfl_xor(qv, o);
  float rs = 1.0f / sqrtf(qv * (1.0f / 768.0f) + 1e-12f);

  float4* o4 = (float4*)(out + (size_t)t * 768);
#pragma unroll
  for (int i = 0; i < 3; i++) {
    float4 g = ((const float4*)lng)[lane + (i << 6)];
    float4 b = ((const float4*)lnb)[lane + (i << 6)];
    float4 r;
    r.x = (v[4 * i] - mu) * rs * g.x + b.x;
    r.y = (v[4 * i + 1] - mu) * rs * g.y + b.y;
    r.z = (v[4 * i + 2] - mu) * rs * g.z + b.z;
    r.w = (v[4 * i + 3] - mu) * rs * g.w + b.w;
    o4[lane + (i << 6)] = r;
  }
}

// ---------------------------------------------------------------------------
extern "C" void kernel_launch(void* const* d_in, const int* in_sizes, int n_in,
                              void* d_out, int out_size, void* d_ws, size_t ws_size,
                              hipStream_t stream) {
  const int BS = in_sizes[3];  // 64*512 = 32768 tokens
  const float* fps    = (const float*)d_in[2];
  const int*   word   = (const int*)d_in[3];
  const float* values = (const float*)d_in[4];
  const int*   tt     = (const int*)d_in[5];
  const int*   pos    = (const int*)d_in[6];
  const float* fc1_w  = (const float*)d_in[7];
  const float* fc1_b  = (const float*)d_in[8];
  const float* fc2_w  = (const float*)d_in[9];
  const float* fc2_b  = (const float*)d_in[10];
  const float* prop   = (const float*)d_in[11];
  const float* valw   = (const float*)d_in[12];
  const float* valb   = (const float*)d_in[13];
  const float* pose   = (const float*)d_in[14];
  const float* tye    = (const float*)d_in[15];
  const float* lng    = (const float*)d_in[16];
  const float* lnb    = (const float*)d_in[17];
  float* out = (float*)d_out;

  char* ws = (char*)d_ws;
  const size_t off_idx  = 256;
  const size_t off_slot = off_idx + (size_t)BS * 4;
  const size_t off_w1t  = off_slot + (size_t)BS * 4;
  const size_t off_w2t  = off_w1t + (size_t)768 * 3072 * 2;
  const size_t off_A1   = off_w2t + (size_t)3072 * 768 * 2;
  const size_t fixed    = off_A1;
  size_t avail = ws_size > fixed ? ws_size - fixed : 0;

  // split-K(4): cap=8192 rows of A1(bf16) + h1(bf16) + 4x bf16 partials
  const size_t per_tok4 = 768 * 2 + 3072 * 2 + 4 * 768 * 2;  // 13824
  const bool splitk = avail >= (size_t)8192 * per_tok4;

  int cap;
  if (splitk) {
    cap = 8192;
  } else {
    const size_t per_tok1 = 768 * 2 + 3072 * 2 + 768 * 2;    // 9216
    long c = (long)(avail / per_tok1);
    c &= ~511L;
    if (c > BS) c = BS;
    if (c < 512) c = 512;
    cap = (int)c;
  }
  const int MBcap = cap / 128;

  const size_t off_h1   = off_A1 + (size_t)cap * 768 * 2;
  const size_t off_sout = off_h1 + (size_t)cap * 3072 * 2;

  int* counter = (int*)(ws + 0);
  int* idx     = (int*)(ws + off_idx);
  int* slot    = (int*)(ws + off_slot);
  unsigned short* w1t = (unsigned short*)(ws + off_w1t);
  unsigned short* w2t = (unsigned short*)(ws + off_w2t);
  unsigned short* A1  = (unsigned short*)(ws + off_A1);
  unsigned short* h1  = (unsigned short*)(ws + off_h1);
  unsigned short* sout = (unsigned short*)(ws + off_sout);

  k_prep<<<4608, 256, 0, stream>>>(fc1_w, fc2_w, w1t, w2t, counter);
  k_compact<<<(BS + 255) / 256, 256, 0, stream>>>(tt, counter, idx, slot, BS);
  k_gather<<<cap / 4, 256, 0, stream>>>(fps, idx, counter, A1, cap);

  // GEMM1: [cap,768] x [768,3072] -> h1 bf16 (+bias,+relu). NCOL=24.
  k_gemm<1, 24, 1, 768, 768><<<24 * MBcap, 256, 0, stream>>>(
      A1, w1t, fc1_b, h1, counter, 3072, cap);

  if (splitk) {
    // GEMM2: [cap,3072] x [3072,768] -> 4 bf16 partials. NCOL=6*4=24.
    k_gemm<0, 6, 4, 3072, 3072><<<24 * MBcap, 256, 0, stream>>>(
        h1, w2t, nullptr, sout, counter, 768, cap);
    k_assemble<4><<<(BS + 3) / 4, 256, 0, stream>>>(
        sout, fc2_b, slot, tt, word, values, pos, prop, valw, valb, pose, tye,
        lng, lnb, out, BS, cap);
  } else {
    k_gemm<0, 6, 1, 3072, 3072><<<6 * MBcap, 256, 0, stream>>>(
        h1, w2t, nullptr, sout, counter, 768, cap);
    k_assemble<1><<<(BS + 3) / 4, 256, 0, stream>>>(
        sout, fc2_b, slot, tt, word, values, pos, prop, valw, valb, pose, tye,
        lng, lnb, out, BS, cap);
  }
}